// Round 9
// baseline (32.092 us; speedup 1.0000x reference)
//
#include <hip/hip_runtime.h>
#include <math.h>

// N=512, IN_F=128, OUT_F=64, H=4.
// Two-node pipeline:
//  K1 (288 blocks): blocks 0-255: ht=h@W^T -> htb bf16 j-pair packed + s1,s2.
//                   blocks 256-287: pack U,V -> bf16 pairs (Ub, Vb).
//  K2 (128 blocks x 1024 thr): block = 4 rows x 4 heads.
//     scores+softmax fully in-register (wave = one (row,head), lane = 8 j)
//     -> aggregate alpha@ht (bf16 pairs) -> c in LDS -> U/V epilogue -> out.
// e_raw[i,j,h] = s1[i][j>>7][h] + s2[j][h]; leaky(0.2), *ew, mask adj,
// softmax_j; c[i,h,f] = sum_j alpha*ht[j,h,f]; out = sigmoid(h U^T + c V^T).

__device__ __forceinline__ float wave_sum(float v) {
    #pragma unroll
    for (int o = 32; o; o >>= 1) v += __shfl_xor(v, o, 64);
    return v;
}
__device__ __forceinline__ float wave_max(float v) {
    #pragma unroll
    for (int o = 32; o; o >>= 1) v = fmaxf(v, __shfl_xor(v, o, 64));
    return v;
}
__device__ __forceinline__ unsigned bf16rn(float x) {   // round-to-nearest-even bf16
    unsigned u = __float_as_uint(x);
    return (u + 0x7fffu + ((u >> 16) & 1u)) >> 16;
}
__device__ __forceinline__ float asf(unsigned u) { return __uint_as_float(u); }

// ---------------- K1 ----------------
__global__ __launch_bounds__(256) void k_transform(
    const float* __restrict__ h, const float* __restrict__ W,
    const float* __restrict__ a, const float* __restrict__ U,
    const float* __restrict__ V,
    unsigned* __restrict__ htb, float* __restrict__ s1, float* __restrict__ s2p,
    unsigned* __restrict__ Ub, unsigned* __restrict__ Vb)
{
    const int t = threadIdx.x;
    if (blockIdx.x >= 256) {   // ---- weight packing tail blocks ----
        const int m = (blockIdx.x - 256) * 256 + t;   // 0..8191
        const float2* U2 = (const float2*)U;
        const float2* V2 = (const float2*)V;
        #pragma unroll
        for (int k = 0; k < 2; ++k) {
            float2 f = U2[m + k * 8192];
            Ub[m + k * 8192] = bf16rn(f.x) | (bf16rn(f.y) << 16);
        }
        #pragma unroll
        for (int k = 0; k < 4; ++k) {
            float2 f = V2[m + k * 8192];
            Vb[m + k * 8192] = bf16rn(f.x) | (bf16rn(f.y) << 16);
        }
        return;
    }
    __shared__ float hsh[2 * 128];
    __shared__ float ash[512];      // a[4][128]
    __shared__ float hts[2 * 256];  // this block's ht rows (f32, for s1/s2)
    const int i0 = blockIdx.x * 2;
    if (t < 64)       ((float4*)hsh)[t]      = ((const float4*)(h + i0 * 128))[t];
    else if (t < 192) ((float4*)ash)[t - 64] = ((const float4*)a)[t - 64];
    __syncthreads();

    float acc0 = 0.f, acc1 = 0.f;
    const float4* Wv = (const float4*)(W + t * 128);
    #pragma unroll
    for (int kk = 0; kk < 32; ++kk) {
        float4 w4 = Wv[kk];
        const float* h0 = hsh + kk * 4;
        const float* h1 = hsh + 128 + kk * 4;
        acc0 += w4.x * h0[0] + w4.y * h0[1] + w4.z * h0[2] + w4.w * h0[3];
        acc1 += w4.x * h1[0] + w4.y * h1[1] + w4.z * h1[2] + w4.w * h1[3];
    }
    // bf16 j-pair pack: low = row 2b, high = row 2b+1, feature t
    htb[blockIdx.x * 256 + t] = bf16rn(acc0) | (bf16rn(acc1) << 16);
    hts[t]       = acc0;
    hts[256 + t] = acc1;
    __syncthreads();

    if (t < 40) {
        const int rr = t & 1, o = t >> 1;
        const float* x;
        const float* y;
        if (o < 16) { x = hts + rr * 256 + (o >> 2) * 64;  y = ash + (o & 3) * 128; }
        else        { x = hts + rr * 256 + (o - 16) * 64;  y = ash + (o - 16) * 128 + 64; }
        float s = 0.f;
        #pragma unroll
        for (int ff = 0; ff < 64; ++ff) {
            int f = (ff + (t << 3)) & 63;   // bank stagger
            s += x[f] * y[f];
        }
        if (o < 16) s1[(i0 + rr) * 16 + (o >> 2) * 4 + (o & 3)] = s;
        else        s2p[(o - 16) * 512 + i0 + rr] = s;
    }
}

// ---------------- K2: fused attention + aggregate + output ----------------
// 128 blocks x 1024 thr (16 waves), block = 4 rows x 4 heads.
__global__ __launch_bounds__(1024) void k_fused(
    const int* __restrict__ adj, const float* __restrict__ ew,
    const unsigned* __restrict__ htb, const float* __restrict__ s1,
    const float* __restrict__ s2p, const float* __restrict__ h,
    const unsigned* __restrict__ Ub, const unsigned* __restrict__ Vb,
    float* __restrict__ out)
{
    __shared__ unsigned attw[16 * 256];   // [rh=r*4+hh][jp] bf16x2   16 KB
    __shared__ float s2sh[4 * 512];       // [hh][j]                   8 KB
    __shared__ float s1sh[64];            // [r][g*4+hh]
    __shared__ float invsh[16];           // [rh]
    __shared__ float scratch[4096];       // part, then psum          16 KB
    __shared__ float hsh[4 * 128];        // h rows                    2 KB
    __shared__ float csh[4 * 256];        // c rows                    4 KB

    const int t = threadIdx.x;
    const int i0 = blockIdx.x * 4;
    const int w = t >> 6, lane = t & 63;

    if (t < 512) ((float4*)s2sh)[t] = ((const float4*)s2p)[t];
    else if (t < 576) s1sh[t - 512] = s1[(i0 + ((t - 512) >> 4)) * 16 + (t & 15)];
    else if (t >= 896) ((float4*)hsh)[t - 896] = ((const float4*)(h + i0 * 128))[t - 896];
    __syncthreads();

    // ---- scores + softmax fully in-register: wave = (r = w>>2, hh = w&3) ----
    {
        const int r = w >> 2, hh = w & 3;
        const int j0 = lane * 8;
        const float s1v = s1sh[r * 16 + (lane >> 4) * 4 + hh];
        float v[8];
        #pragma unroll
        for (int q = 0; q < 2; ++q) {
            const int jq = j0 + q * 4;
            int4   av = *(const int4*)  (adj + (i0 + r) * 512 + jq);
            float4 wv = *(const float4*)(ew  + (i0 + r) * 512 + jq);
            float4 sv = *(const float4*)&s2sh[hh * 512 + jq];
            float e;
            e = s1v + sv.x; e = (e >= 0.f) ? e : 0.2f * e; e *= wv.x; v[q*4+0] = (av.x > 0) ? e : -9.0e15f;
            e = s1v + sv.y; e = (e >= 0.f) ? e : 0.2f * e; e *= wv.y; v[q*4+1] = (av.y > 0) ? e : -9.0e15f;
            e = s1v + sv.z; e = (e >= 0.f) ? e : 0.2f * e; e *= wv.z; v[q*4+2] = (av.z > 0) ? e : -9.0e15f;
            e = s1v + sv.w; e = (e >= 0.f) ? e : 0.2f * e; e *= wv.w; v[q*4+3] = (av.w > 0) ? e : -9.0e15f;
        }
        float m = v[0];
        #pragma unroll
        for (int k = 1; k < 8; ++k) m = fmaxf(m, v[k]);
        m = wave_max(m);
        float s = 0.f;
        #pragma unroll
        for (int k = 0; k < 8; ++k) { v[k] = __expf(v[k] - m); s += v[k]; }
        s = wave_sum(s);
        if (lane == 0) invsh[w] = 1.f / s;
        uint4 pk;
        pk.x = bf16rn(v[0]) | (bf16rn(v[1]) << 16);
        pk.y = bf16rn(v[2]) | (bf16rn(v[3]) << 16);
        pk.z = bf16rn(v[4]) | (bf16rn(v[5]) << 16);
        pk.w = bf16rn(v[6]) | (bf16rn(v[7]) << 16);
        *(uint4*)&attw[w * 256 + lane * 4] = pk;
    }
    __syncthreads();

    // ---- aggregate: wave = (hh = w&3, j-quarter q = w>>2), all 4 rows ----
    {
        const int hh = w & 3, q = w >> 2;
        float p[4] = {0.f, 0.f, 0.f, 0.f};
        const unsigned* hb = htb + hh * 64 + lane;
        const int jp0 = q * 64;
        for (int c8 = 0; c8 < 64; c8 += 8) {
            unsigned hv[8];
            #pragma unroll
            for (int u = 0; u < 8; ++u) hv[u] = hb[(jp0 + c8 + u) * 256];
            #pragma unroll
            for (int r = 0; r < 4; ++r) {
                unsigned aa[8];
                *(uint4*)&aa[0] = *(const uint4*)&attw[(r * 4 + hh) * 256 + jp0 + c8];
                *(uint4*)&aa[4] = *(const uint4*)&attw[(r * 4 + hh) * 256 + jp0 + c8 + 4];
                #pragma unroll
                for (int u = 0; u < 8; ++u) {
                    p[r] += asf(aa[u] << 16) * asf(hv[u] << 16)
                          + asf(aa[u] & 0xffff0000u) * asf(hv[u] & 0xffff0000u);
                }
            }
        }
        #pragma unroll
        for (int r = 0; r < 4; ++r) scratch[(q * 4 + r) * 256 + hh * 64 + lane] = p[r];
    }
    __syncthreads();

    // ---- combine partials -> c rows ----
    {
        const int r = t >> 8, cc = t & 255;
        float cv = scratch[r * 256 + cc] + scratch[(4 + r) * 256 + cc]
                 + scratch[(8 + r) * 256 + cc] + scratch[(12 + r) * 256 + cc];
        csh[r * 256 + cc] = cv * invsh[r * 4 + (cc >> 6)];
    }
    __syncthreads();

    // ---- epilogue: thread = (K-quarter kq = t>>8, col = t&255), 4 rows ----
    {
        const int kq = t >> 8, col = t & 255;
        float acc[4] = {0.f, 0.f, 0.f, 0.f};
        // U part: k in [kq*32, kq*32+32) -> 16 u32 pairs
        {
            const uint4* Up = (const uint4*)(Ub + col * 64 + kq * 16);
            #pragma unroll
            for (int b4 = 0; b4 < 4; ++b4) {
                uint4 uv = Up[b4];
                unsigned ua[4] = {uv.x, uv.y, uv.z, uv.w};
                #pragma unroll
                for (int e = 0; e < 4; ++e) {
                    const int k = kq * 32 + b4 * 8 + e * 2;
                    float ulo = asf(ua[e] << 16), uhi = asf(ua[e] & 0xffff0000u);
                    #pragma unroll
                    for (int r = 0; r < 4; ++r)
                        acc[r] += ulo * hsh[r * 128 + k] + uhi * hsh[r * 128 + k + 1];
                }
            }
        }
        // V part: k in [kq*64, kq*64+64) -> 32 u32 pairs
        {
            const uint4* Vp = (const uint4*)(Vb + col * 128 + kq * 32);
            #pragma unroll
            for (int b4 = 0; b4 < 8; ++b4) {
                uint4 vv = Vp[b4];
                unsigned va[4] = {vv.x, vv.y, vv.z, vv.w};
                #pragma unroll
                for (int e = 0; e < 4; ++e) {
                    const int k = kq * 64 + b4 * 8 + e * 2;
                    float vlo = asf(va[e] << 16), vhi = asf(va[e] & 0xffff0000u);
                    #pragma unroll
                    for (int r = 0; r < 4; ++r)
                        acc[r] += vlo * csh[r * 256 + k] + vhi * csh[r * 256 + k + 1];
                }
            }
        }
        #pragma unroll
        for (int r = 0; r < 4; ++r) scratch[(kq * 4 + r) * 256 + col] = acc[r];
    }
    __syncthreads();

    // ---- final combine + sigmoid ----
    {
        const int r = t >> 8, col = t & 255;
        float x = scratch[r * 256 + col] + scratch[(4 + r) * 256 + col]
                + scratch[(8 + r) * 256 + col] + scratch[(12 + r) * 256 + col];
        out[(i0 + r) * 256 + col] = 1.f / (1.f + __expf(-x));
    }
}

extern "C" void kernel_launch(void* const* d_in, const int* in_sizes, int n_in,
                              void* d_out, int out_size, void* d_ws, size_t ws_size,
                              hipStream_t stream) {
    const float* h   = (const float*)d_in[0];
    const int*   adj = (const int*)d_in[1];
    const float* ew  = (const float*)d_in[2];
    const float* W   = (const float*)d_in[3];
    const float* a   = (const float*)d_in[4];
    const float* U   = (const float*)d_in[5];
    const float* V   = (const float*)d_in[6];
    float* out = (float*)d_out;

    unsigned* htb = (unsigned*)d_ws;          // 256*256 u32 (ht bf16 j-pairs)
    float* s1  = (float*)(htb + 256 * 256);   // 512*16
    float* s2p = s1 + 512 * 16;               // 4*512
    unsigned* Ub = (unsigned*)(s2p + 4 * 512);// 16384 u32
    unsigned* Vb = Ub + 16384;                // 32768 u32

    k_transform<<<288, 256, 0, stream>>>(h, W, a, U, V, htb, s1, s2p, Ub, Vb);
    k_fused<<<128, 1024, 0, stream>>>(adj, ew, htb, s1, s2p, h, Ub, Vb, out);
}